// Round 1
// 647.367 us; speedup vs baseline: 1.0328x; 1.0328x over previous
//
#include <hip/hip_runtime.h>
#include <math.h>

// ECE loss: logits [N=131072, C=1000] fp32, target [N] int32.
// Outputs (fp32, concat): [ece, mean(confidence), mean(accuracy)]  (3 floats)
//
// HBM-bound: 524 MB logits read once -> floor ~83 us @ 6.3 TB/s.
// One wave per row, 16 rows per wave (grid-stride). Two-phase softmax.
// This revision vs. previous:
//  - last loop iteration peeled so the next-row prefetch is UNCONDITIONAL
//    (statically-counted vmcnt; no branchy prefetch -> no conservative
//    vmcnt(0) drain before each row's compute)
//  - nontemporal loads for the read-once logits stream
//  - the 5 per-row bin accumulates issue as ONE ds_add_f32 across lanes 0..4
//    (distinct LDS slots, <=2-way bank alias = free) instead of 5 serial
//    lane-0 atomics
//  - per-row exp/sum arithmetic kept bit-identical to the passing version

constexpr int N_CLASSES = 1000;
constexpr int NBINS     = 15;
constexpr int BLOCK     = 256;
constexpr int GRID      = 2048;
constexpr int WS_FLOATS = 3 * NBINS + 2;   // counts[15], sum_conf[15], sum_acc[15], conf_tot, acc_tot
constexpr int ROW_VEC   = N_CLASSES / 4;   // 250 float4 per row

typedef float f32x4 __attribute__((ext_vector_type(4)));

__device__ __forceinline__ f32x4 ntld(const f32x4* p) {
    return __builtin_nontemporal_load(p);
}

__device__ __forceinline__ void process_row(f32x4 a, f32x4 b, f32x4 c, f32x4 d,
                                            int lane, int my_tgt, int k,
                                            float* sacc) {
    float xs[16];
    xs[0]  = a.x; xs[1]  = a.y; xs[2]  = a.z; xs[3]  = a.w;
    xs[4]  = b.x; xs[5]  = b.y; xs[6]  = b.z; xs[7]  = b.w;
    xs[8]  = c.x; xs[9]  = c.y; xs[10] = c.z; xs[11] = c.w;
    xs[12] = d.x; xs[13] = d.y; xs[14] = d.z; xs[15] = d.w;
    if (lane >= 58) { xs[12] = xs[13] = xs[14] = xs[15] = -INFINITY; }

    // ---- phase 1: wave max (max is exact-associative; tree order is free) ----
    float m = xs[0];
    #pragma unroll
    for (int j = 1; j < 16; ++j) m = fmaxf(m, xs[j]);
    #pragma unroll
    for (int off = 32; off > 0; off >>= 1) m = fmaxf(m, __shfl_xor(m, off));

    // ---- phase 2: independent exps + sum + first-occurrence argmax ----
    // (summation order identical to the previously-verified kernel)
    float s   = 0.0f;
    int   idx = 0x7fffffff;
    #pragma unroll
    for (int cc = 0; cc < 4; ++cc) {
        #pragma unroll
        for (int j = 0; j < 4; ++j) {
            const int   q = cc * 4 + j;
            const float x = xs[q];
            s += __expf(x - m);
            const int e = cc * 256 + lane * 4 + j;
            if (x == m && e < idx) idx = e;
        }
    }
    #pragma unroll
    for (int off = 32; off > 0; off >>= 1) {
        s   += __shfl_xor(s, off);
        idx  = min(idx, __shfl_xor(idx, off));
    }

    const int   tr   = __shfl(my_tgt, k);    // this row's target, no global load
    const float conf = 1.0f / s;             // probs[argmax] = exp(m - lse) = 1/sum
    const float acc  = (idx == tr) ? 1.0f : 0.0f;
    int bin = (int)ceilf(conf * (float)NBINS) - 1;   // (lower, upper] membership
    bin = bin < 0 ? 0 : (bin > NBINS - 1 ? NBINS - 1 : bin);

    // 5 accumulates as a single wave LDS atomic: lanes 0..4, distinct slots.
    if (lane < 5) {
        const int slot = (lane == 0) ? bin
                       : (lane == 1) ? NBINS + bin
                       : (lane == 2) ? 2 * NBINS + bin
                       : (lane == 3) ? 3 * NBINS
                       :               3 * NBINS + 1;
        const float val = (lane == 0) ? 1.0f
                        : (lane == 1 || lane == 3) ? conf
                        : acc;
        atomicAdd(&sacc[slot], val);
    }
}

__global__ __launch_bounds__(BLOCK) void ece_rows(const float* __restrict__ logits,
                                                  const int*   __restrict__ target,
                                                  float*       __restrict__ ws,
                                                  int nrows) {
    __shared__ float sacc[WS_FLOATS];
    const int t = threadIdx.x;
    if (t < WS_FLOATS) sacc[t] = 0.0f;
    __syncthreads();

    const int lane   = t & 63;
    const int wave   = t >> 6;
    const int gw     = blockIdx.x * (BLOCK / 64) + wave;
    const int nwaves = gridDim.x * (BLOCK / 64);

    // Per-wave target gather: lane k holds the target of this wave's k-th row.
    const int rk     = gw + lane * nwaves;
    const int my_tgt = (rk < nrows) ? target[rk] : -1;

    // chunk-3 clamped float4 index: lanes >= 58 re-read the last vector (masked)
    int c3 = 192 + lane;
    if (c3 > 249) c3 = 249;

    if (gw < nrows) {
        const f32x4* rowp = reinterpret_cast<const f32x4*>(logits) + (size_t)gw * ROW_VEC;
        const size_t step = (size_t)nwaves * ROW_VEC;

        f32x4 cur0 = ntld(rowp + lane);
        f32x4 cur1 = ntld(rowp + 64 + lane);
        f32x4 cur2 = ntld(rowp + 128 + lane);
        f32x4 cur3 = ntld(rowp + c3);

        int r = gw, k = 0;
        // main loop: next row always exists -> unconditional prefetch,
        // statically-counted vmcnt, zero branches around the loads
        for (; r + nwaves < nrows; r += nwaves, ++k) {
            const f32x4* np = rowp + step;
            f32x4 nxt0 = ntld(np + lane);
            f32x4 nxt1 = ntld(np + 64 + lane);
            f32x4 nxt2 = ntld(np + 128 + lane);
            f32x4 nxt3 = ntld(np + c3);

            process_row(cur0, cur1, cur2, cur3, lane, my_tgt, k, sacc);

            cur0 = nxt0; cur1 = nxt1; cur2 = nxt2; cur3 = nxt3;
            rowp = np;
        }
        // peeled last row: no prefetch
        process_row(cur0, cur1, cur2, cur3, lane, my_tgt, k, sacc);
    }

    __syncthreads();
    if (t < WS_FLOATS) atomicAdd(&ws[t], sacc[t]);
}

__global__ void ece_finalize(const float* __restrict__ ws,
                             float*       __restrict__ out,
                             float inv_n) {
    const int t = threadIdx.x;
    float per = 0.0f;
    if (t < NBINS) {
        float c  = ws[t];
        float sc = ws[NBINS + t];
        float sa = ws[2 * NBINS + t];
        if (c > 0.0f) {
            float safe = fmaxf(c, 1.0f);
            per = (sc / safe - sa / safe) * (c * inv_n);   // (avg_conf - acc) * prop_in_bin
        }
    }
    #pragma unroll
    for (int off = 32; off > 0; off >>= 1) per += __shfl_xor(per, off);
    if (t == 0) {
        out[0] = per;
        out[1] = ws[3 * NBINS]     * inv_n;
        out[2] = ws[3 * NBINS + 1] * inv_n;
    }
}

extern "C" void kernel_launch(void* const* d_in, const int* in_sizes, int n_in,
                              void* d_out, int out_size, void* d_ws, size_t ws_size,
                              hipStream_t stream) {
    const float* logits = (const float*)d_in[0];
    const int*   target = (const int*)d_in[1];
    float*       ws     = (float*)d_ws;
    float*       out    = (float*)d_out;
    const int nrows = in_sizes[1];

    hipMemsetAsync(ws, 0, WS_FLOATS * sizeof(float), stream);
    ece_rows<<<GRID, BLOCK, 0, stream>>>(logits, target, ws, nrows);
    ece_finalize<<<1, 64, 0, stream>>>(ws, out, 1.0f / (float)nrows);
}

// Round 2
// 642.604 us; speedup vs baseline: 1.0405x; 1.0074x over previous
//
#include <hip/hip_runtime.h>
#include <math.h>

// ECE loss: logits [N=131072, C=1000] fp32, target [N] int32.
// Outputs (fp32, concat): [ece, mean(confidence), mean(accuracy)]  (3 floats)
//
// HBM-bound: 524 MB logits read once -> floor ~83 us @ 6.3 TB/s.
// One wave per row, 16 rows per wave. Two-phase softmax (wave max, then
// independent exps).
// This revision vs. previous:
//  - rows processed in PAIRS with the two rows' 6-stage shuffle-reduce
//    chains interleaved at source: the dependent ds_swizzle latency of the
//    butterfly (the per-row serial tail) overlaps across the pair
//  - prefetch depth 2: the next PAIR (8 KB/wave) is issued before the
//    current pair's compute, doubling per-wave bytes in flight
//  - __launch_bounds__(256,4) pins the allocator <=128 VGPR so occupancy
//    stays at 4 waves/SIMD with A,B,A2,B2 (64 regs) live
//  - per-row max/exp/sum association order identical to the verified
//    kernel -> conf/bin/acc bit-identical

constexpr int N_CLASSES = 1000;
constexpr int NBINS     = 15;
constexpr int BLOCK     = 256;
constexpr int GRID      = 2048;
constexpr int WS_FLOATS = 3 * NBINS + 2;   // counts[15], sum_conf[15], sum_acc[15], conf_tot, acc_tot
constexpr int ROW_VEC   = N_CLASSES / 4;   // 250 float4 per row

typedef float f32x4 __attribute__((ext_vector_type(4)));

struct Row { f32x4 v0, v1, v2, v3; };

__device__ __forceinline__ f32x4 ntld(const f32x4* p) {
    return __builtin_nontemporal_load(p);
}

__device__ __forceinline__ Row load_row(const f32x4* p, int lane, int c3) {
    Row r;
    r.v0 = ntld(p + lane);
    r.v1 = ntld(p + 64 + lane);
    r.v2 = ntld(p + 128 + lane);
    r.v3 = ntld(p + c3);
    return r;
}

__device__ __forceinline__ void unpack16(const Row& r, float xs[16], int lane) {
    xs[0]  = r.v0.x; xs[1]  = r.v0.y; xs[2]  = r.v0.z; xs[3]  = r.v0.w;
    xs[4]  = r.v1.x; xs[5]  = r.v1.y; xs[6]  = r.v1.z; xs[7]  = r.v1.w;
    xs[8]  = r.v2.x; xs[9]  = r.v2.y; xs[10] = r.v2.z; xs[11] = r.v2.w;
    xs[12] = r.v3.x; xs[13] = r.v3.y; xs[14] = r.v3.z; xs[15] = r.v3.w;
    if (lane >= 58) { xs[12] = xs[13] = xs[14] = xs[15] = -INFINITY; }
}

__device__ __forceinline__ void bin_accumulate(float conf, float acc, int lane5,
                                               float* sacc) {
    // 5 accumulates as one wave LDS atomic across 5 lanes, distinct slots.
    int bin = (int)ceilf(conf * (float)NBINS) - 1;   // (lower, upper] membership
    bin = bin < 0 ? 0 : (bin > NBINS - 1 ? NBINS - 1 : bin);
    const int slot = (lane5 == 0) ? bin
                   : (lane5 == 1) ? NBINS + bin
                   : (lane5 == 2) ? 2 * NBINS + bin
                   : (lane5 == 3) ? 3 * NBINS
                   :                3 * NBINS + 1;
    const float val = (lane5 == 0) ? 1.0f
                    : (lane5 == 1 || lane5 == 3) ? conf
                    : acc;
    atomicAdd(&sacc[slot], val);
}

__device__ __forceinline__ void process_two(const Row& A, const Row& B,
                                            int lane, int trA, int trB,
                                            float* sacc) {
    float xa[16], xb[16];
    unpack16(A, xa, lane);
    unpack16(B, xb, lane);

    // ---- phase 1: wave max, both rows interleaved (max is exact-assoc) ----
    float ma = xa[0], mb = xb[0];
    #pragma unroll
    for (int j = 1; j < 16; ++j) { ma = fmaxf(ma, xa[j]); mb = fmaxf(mb, xb[j]); }
    #pragma unroll
    for (int off = 32; off > 0; off >>= 1) {
        ma = fmaxf(ma, __shfl_xor(ma, off));
        mb = fmaxf(mb, __shfl_xor(mb, off));
    }

    // ---- phase 2: independent exps + sum + first-occurrence argmax ----
    // (per-row summation order identical to the verified kernel)
    float sa = 0.0f, sb = 0.0f;
    int   ia = 0x7fffffff, ib = 0x7fffffff;
    #pragma unroll
    for (int cc = 0; cc < 4; ++cc) {
        #pragma unroll
        for (int j = 0; j < 4; ++j) {
            const int   q = cc * 4 + j;
            const int   e = cc * 256 + lane * 4 + j;
            const float va = xa[q];
            sa += __expf(va - ma);
            if (va == ma && e < ia) ia = e;
            const float vb = xb[q];
            sb += __expf(vb - mb);
            if (vb == mb && e < ib) ib = e;
        }
    }
    #pragma unroll
    for (int off = 32; off > 0; off >>= 1) {
        sa += __shfl_xor(sa, off);
        ia  = min(ia, __shfl_xor(ia, off));
        sb += __shfl_xor(sb, off);
        ib  = min(ib, __shfl_xor(ib, off));
    }

    const float confA = 1.0f / sa;           // probs[argmax] = 1/sum
    const float confB = 1.0f / sb;
    const float accA  = (ia == trA) ? 1.0f : 0.0f;
    const float accB  = (ib == trB) ? 1.0f : 0.0f;

    const int l8 = lane - 8;
    if (lane < 5)            bin_accumulate(confA, accA, lane, sacc);
    else if (l8 >= 0 && l8 < 5) bin_accumulate(confB, accB, l8, sacc);
}

__device__ __forceinline__ void process_one(const Row& A, int lane, int trA,
                                            float* sacc) {
    float xa[16];
    unpack16(A, xa, lane);
    float ma = xa[0];
    #pragma unroll
    for (int j = 1; j < 16; ++j) ma = fmaxf(ma, xa[j]);
    #pragma unroll
    for (int off = 32; off > 0; off >>= 1) ma = fmaxf(ma, __shfl_xor(ma, off));

    float sa = 0.0f;
    int   ia = 0x7fffffff;
    #pragma unroll
    for (int cc = 0; cc < 4; ++cc) {
        #pragma unroll
        for (int j = 0; j < 4; ++j) {
            const int   q = cc * 4 + j;
            const int   e = cc * 256 + lane * 4 + j;
            const float va = xa[q];
            sa += __expf(va - ma);
            if (va == ma && e < ia) ia = e;
        }
    }
    #pragma unroll
    for (int off = 32; off > 0; off >>= 1) {
        sa += __shfl_xor(sa, off);
        ia  = min(ia, __shfl_xor(ia, off));
    }
    const float confA = 1.0f / sa;
    const float accA  = (ia == trA) ? 1.0f : 0.0f;
    if (lane < 5) bin_accumulate(confA, accA, lane, sacc);
}

__global__ __launch_bounds__(BLOCK, 4) void ece_rows(const float* __restrict__ logits,
                                                     const int*   __restrict__ target,
                                                     float*       __restrict__ ws,
                                                     int nrows) {
    __shared__ float sacc[WS_FLOATS];
    const int t = threadIdx.x;
    if (t < WS_FLOATS) sacc[t] = 0.0f;
    __syncthreads();

    const int lane   = t & 63;
    const int wave   = t >> 6;
    const int gw     = blockIdx.x * (BLOCK / 64) + wave;
    const int nwaves = gridDim.x * (BLOCK / 64);

    // Per-wave target gather: lane k holds the target of this wave's k-th row.
    const int rk     = gw + lane * nwaves;
    const int my_tgt = (rk < nrows) ? target[rk] : -1;

    // chunk-3 clamped float4 index: lanes >= 58 re-read the last vector (masked)
    int c3 = 192 + lane;
    if (c3 > 249) c3 = 249;

    if (gw < nrows) {
        const f32x4* base = reinterpret_cast<const f32x4*>(logits) + (size_t)gw * ROW_VEC;
        const size_t step = (size_t)nwaves * ROW_VEC;
        const int nk = (nrows - 1 - gw) / nwaves + 1;   // rows this wave owns

        if (nk >= 2) {
            Row A = load_row(base, lane, c3);
            Row B = load_row(base + step, lane, c3);
            const f32x4* p = base;
            int k = 0;
            // main loop: next full pair exists -> unconditional depth-2 prefetch
            while (k + 3 < nk) {
                const f32x4* p2 = p + 2 * step;
                Row A2 = load_row(p2, lane, c3);
                Row B2 = load_row(p2 + step, lane, c3);
                const int trA = __shfl(my_tgt, k);
                const int trB = __shfl(my_tgt, k + 1);
                process_two(A, B, lane, trA, trB, sacc);
                A = A2; B = B2; p = p2; k += 2;
            }
            if (k + 2 < nk) {          // 3 rows remain
                Row C = load_row(p + 2 * step, lane, c3);
                process_two(A, B, lane, __shfl(my_tgt, k), __shfl(my_tgt, k + 1), sacc);
                process_one(C, lane, __shfl(my_tgt, k + 2), sacc);
            } else {                   // exactly 2 rows remain
                process_two(A, B, lane, __shfl(my_tgt, k), __shfl(my_tgt, k + 1), sacc);
            }
        } else {
            Row A = load_row(base, lane, c3);
            process_one(A, lane, __shfl(my_tgt, 0), sacc);
        }
    }

    __syncthreads();
    if (t < WS_FLOATS) atomicAdd(&ws[t], sacc[t]);
}

__global__ void ece_finalize(const float* __restrict__ ws,
                             float*       __restrict__ out,
                             float inv_n) {
    const int t = threadIdx.x;
    float per = 0.0f;
    if (t < NBINS) {
        float c  = ws[t];
        float sc = ws[NBINS + t];
        float sa = ws[2 * NBINS + t];
        if (c > 0.0f) {
            float safe = fmaxf(c, 1.0f);
            per = (sc / safe - sa / safe) * (c * inv_n);   // (avg_conf - acc) * prop_in_bin
        }
    }
    #pragma unroll
    for (int off = 32; off > 0; off >>= 1) per += __shfl_xor(per, off);
    if (t == 0) {
        out[0] = per;
        out[1] = ws[3 * NBINS]     * inv_n;
        out[2] = ws[3 * NBINS + 1] * inv_n;
    }
}

extern "C" void kernel_launch(void* const* d_in, const int* in_sizes, int n_in,
                              void* d_out, int out_size, void* d_ws, size_t ws_size,
                              hipStream_t stream) {
    const float* logits = (const float*)d_in[0];
    const int*   target = (const int*)d_in[1];
    float*       ws     = (float*)d_ws;
    float*       out    = (float*)d_out;
    const int nrows = in_sizes[1];

    hipMemsetAsync(ws, 0, WS_FLOATS * sizeof(float), stream);
    ece_rows<<<GRID, BLOCK, 0, stream>>>(logits, target, ws, nrows);
    ece_finalize<<<1, 64, 0, stream>>>(ws, out, 1.0f / (float)nrows);
}

// Round 3
// 634.840 us; speedup vs baseline: 1.0532x; 1.0122x over previous
//
#include <hip/hip_runtime.h>
#include <math.h>

// ECE loss: logits [N=131072, C=1000] fp32, target [N] int32.
// Outputs (fp32, concat): [ece, mean(confidence), mean(accuracy)]  (3 floats)
//
// HBM-bound: 524 MB logits read once -> floor ~83 us @ 6.3 TB/s.
// One wave per row, 16 rows per wave. Two-phase softmax (wave max, then
// independent exps), rows processed in pairs with interleaved reduce chains,
// depth-2 pair prefetch.
// This revision vs. previous:
//  - per-block PARTIAL WRITES (ws[block*48+slot] = partial) instead of
//    global atomicAdd into 47 shared words: kills the hipMemsetAsync
//    dispatch (no zeroing needed -- pure overwrite) and the ~96K
//    same-address global-atomic tail
//  - finalize upgraded to one 256-thread block that tree-reduces the
//    2048x48 partials (LDS transpose padded +1 to keep the 47-lane column
//    reduction bank-conflict-free)
//  - per-row conf/bin/acc math bit-identical to the verified kernel

constexpr int N_CLASSES = 1000;
constexpr int NBINS     = 15;
constexpr int BLOCK     = 256;
constexpr int GRID      = 2048;
constexpr int WS_FLOATS = 3 * NBINS + 2;   // counts[15], sum_conf[15], sum_acc[15], conf_tot, acc_tot
constexpr int WS_STRIDE = 48;              // padded per-block partial stride
constexpr int ROW_VEC   = N_CLASSES / 4;   // 250 float4 per row

typedef float f32x4 __attribute__((ext_vector_type(4)));

struct Row { f32x4 v0, v1, v2, v3; };

__device__ __forceinline__ f32x4 ntld(const f32x4* p) {
    return __builtin_nontemporal_load(p);
}

__device__ __forceinline__ Row load_row(const f32x4* p, int lane, int c3) {
    Row r;
    r.v0 = ntld(p + lane);
    r.v1 = ntld(p + 64 + lane);
    r.v2 = ntld(p + 128 + lane);
    r.v3 = ntld(p + c3);
    return r;
}

__device__ __forceinline__ void unpack16(const Row& r, float xs[16], int lane) {
    xs[0]  = r.v0.x; xs[1]  = r.v0.y; xs[2]  = r.v0.z; xs[3]  = r.v0.w;
    xs[4]  = r.v1.x; xs[5]  = r.v1.y; xs[6]  = r.v1.z; xs[7]  = r.v1.w;
    xs[8]  = r.v2.x; xs[9]  = r.v2.y; xs[10] = r.v2.z; xs[11] = r.v2.w;
    xs[12] = r.v3.x; xs[13] = r.v3.y; xs[14] = r.v3.z; xs[15] = r.v3.w;
    if (lane >= 58) { xs[12] = xs[13] = xs[14] = xs[15] = -INFINITY; }
}

__device__ __forceinline__ void bin_accumulate(float conf, float acc, int lane5,
                                               float* sacc) {
    // 5 accumulates as one wave LDS atomic across 5 lanes, distinct slots.
    int bin = (int)ceilf(conf * (float)NBINS) - 1;   // (lower, upper] membership
    bin = bin < 0 ? 0 : (bin > NBINS - 1 ? NBINS - 1 : bin);
    const int slot = (lane5 == 0) ? bin
                   : (lane5 == 1) ? NBINS + bin
                   : (lane5 == 2) ? 2 * NBINS + bin
                   : (lane5 == 3) ? 3 * NBINS
                   :                3 * NBINS + 1;
    const float val = (lane5 == 0) ? 1.0f
                    : (lane5 == 1 || lane5 == 3) ? conf
                    : acc;
    atomicAdd(&sacc[slot], val);
}

__device__ __forceinline__ void process_two(const Row& A, const Row& B,
                                            int lane, int trA, int trB,
                                            float* sacc) {
    float xa[16], xb[16];
    unpack16(A, xa, lane);
    unpack16(B, xb, lane);

    // ---- phase 1: wave max, both rows interleaved (max is exact-assoc) ----
    float ma = xa[0], mb = xb[0];
    #pragma unroll
    for (int j = 1; j < 16; ++j) { ma = fmaxf(ma, xa[j]); mb = fmaxf(mb, xb[j]); }
    #pragma unroll
    for (int off = 32; off > 0; off >>= 1) {
        ma = fmaxf(ma, __shfl_xor(ma, off));
        mb = fmaxf(mb, __shfl_xor(mb, off));
    }

    // ---- phase 2: independent exps + sum + first-occurrence argmax ----
    float sa = 0.0f, sb = 0.0f;
    int   ia = 0x7fffffff, ib = 0x7fffffff;
    #pragma unroll
    for (int cc = 0; cc < 4; ++cc) {
        #pragma unroll
        for (int j = 0; j < 4; ++j) {
            const int   q = cc * 4 + j;
            const int   e = cc * 256 + lane * 4 + j;
            const float va = xa[q];
            sa += __expf(va - ma);
            if (va == ma && e < ia) ia = e;
            const float vb = xb[q];
            sb += __expf(vb - mb);
            if (vb == mb && e < ib) ib = e;
        }
    }
    #pragma unroll
    for (int off = 32; off > 0; off >>= 1) {
        sa += __shfl_xor(sa, off);
        ia  = min(ia, __shfl_xor(ia, off));
        sb += __shfl_xor(sb, off);
        ib  = min(ib, __shfl_xor(ib, off));
    }

    const float confA = 1.0f / sa;           // probs[argmax] = 1/sum
    const float confB = 1.0f / sb;
    const float accA  = (ia == trA) ? 1.0f : 0.0f;
    const float accB  = (ib == trB) ? 1.0f : 0.0f;

    const int l8 = lane - 8;
    if (lane < 5)               bin_accumulate(confA, accA, lane, sacc);
    else if (l8 >= 0 && l8 < 5) bin_accumulate(confB, accB, l8, sacc);
}

__device__ __forceinline__ void process_one(const Row& A, int lane, int trA,
                                            float* sacc) {
    float xa[16];
    unpack16(A, xa, lane);
    float ma = xa[0];
    #pragma unroll
    for (int j = 1; j < 16; ++j) ma = fmaxf(ma, xa[j]);
    #pragma unroll
    for (int off = 32; off > 0; off >>= 1) ma = fmaxf(ma, __shfl_xor(ma, off));

    float sa = 0.0f;
    int   ia = 0x7fffffff;
    #pragma unroll
    for (int cc = 0; cc < 4; ++cc) {
        #pragma unroll
        for (int j = 0; j < 4; ++j) {
            const int   q = cc * 4 + j;
            const int   e = cc * 256 + lane * 4 + j;
            const float va = xa[q];
            sa += __expf(va - ma);
            if (va == ma && e < ia) ia = e;
        }
    }
    #pragma unroll
    for (int off = 32; off > 0; off >>= 1) {
        sa += __shfl_xor(sa, off);
        ia  = min(ia, __shfl_xor(ia, off));
    }
    const float confA = 1.0f / sa;
    const float accA  = (ia == trA) ? 1.0f : 0.0f;
    if (lane < 5) bin_accumulate(confA, accA, lane, sacc);
}

__global__ __launch_bounds__(BLOCK, 4) void ece_rows(const float* __restrict__ logits,
                                                     const int*   __restrict__ target,
                                                     float*       __restrict__ ws,
                                                     int nrows) {
    __shared__ float sacc[WS_FLOATS];
    const int t = threadIdx.x;
    if (t < WS_FLOATS) sacc[t] = 0.0f;
    __syncthreads();

    const int lane   = t & 63;
    const int wave   = t >> 6;
    const int gw     = blockIdx.x * (BLOCK / 64) + wave;
    const int nwaves = gridDim.x * (BLOCK / 64);

    // Per-wave target gather: lane k holds the target of this wave's k-th row.
    const int rk     = gw + lane * nwaves;
    const int my_tgt = (rk < nrows) ? target[rk] : -1;

    // chunk-3 clamped float4 index: lanes >= 58 re-read the last vector (masked)
    int c3 = 192 + lane;
    if (c3 > 249) c3 = 249;

    if (gw < nrows) {
        const f32x4* base = reinterpret_cast<const f32x4*>(logits) + (size_t)gw * ROW_VEC;
        const size_t step = (size_t)nwaves * ROW_VEC;
        const int nk = (nrows - 1 - gw) / nwaves + 1;   // rows this wave owns

        if (nk >= 2) {
            Row A = load_row(base, lane, c3);
            Row B = load_row(base + step, lane, c3);
            const f32x4* p = base;
            int k = 0;
            while (k + 3 < nk) {
                const f32x4* p2 = p + 2 * step;
                Row A2 = load_row(p2, lane, c3);
                Row B2 = load_row(p2 + step, lane, c3);
                const int trA = __shfl(my_tgt, k);
                const int trB = __shfl(my_tgt, k + 1);
                process_two(A, B, lane, trA, trB, sacc);
                A = A2; B = B2; p = p2; k += 2;
            }
            if (k + 2 < nk) {          // 3 rows remain
                Row C = load_row(p + 2 * step, lane, c3);
                process_two(A, B, lane, __shfl(my_tgt, k), __shfl(my_tgt, k + 1), sacc);
                process_one(C, lane, __shfl(my_tgt, k + 2), sacc);
            } else {                   // exactly 2 rows remain
                process_two(A, B, lane, __shfl(my_tgt, k), __shfl(my_tgt, k + 1), sacc);
            }
        } else {
            Row A = load_row(base, lane, c3);
            process_one(A, lane, __shfl(my_tgt, 0), sacc);
        }
    }

    __syncthreads();
    // Per-block partial WRITE (no read-modify-write -> no ws zeroing needed).
    if (t < WS_STRIDE) {
        const float v = (t < WS_FLOATS) ? sacc[t] : 0.0f;
        ws[(size_t)blockIdx.x * WS_STRIDE + t] = v;
    }
}

__global__ __launch_bounds__(256) void ece_finalize(const float* __restrict__ ws,
                                                    float*       __restrict__ out,
                                                    float inv_n) {
    // Reduce GRID x 48 partials. LDS transposed with +1 pad so the 47-lane
    // column reduction is bank-conflict-free.
    __shared__ float red[WS_STRIDE * 257];
    __shared__ float fin[WS_STRIDE];
    const int t = threadIdx.x;

    float loc[WS_STRIDE];
    #pragma unroll
    for (int i = 0; i < WS_STRIDE; ++i) loc[i] = 0.0f;
    for (int b = t; b < GRID; b += 256) {
        const float* p = ws + (size_t)b * WS_STRIDE;
        #pragma unroll
        for (int i = 0; i < WS_STRIDE; ++i) loc[i] += p[i];
    }
    #pragma unroll
    for (int i = 0; i < WS_STRIDE; ++i) red[i * 257 + t] = loc[i];
    __syncthreads();

    if (t < WS_FLOATS) {
        const float* r = red + t * 257;
        float s0 = 0.0f, s1 = 0.0f, s2 = 0.0f, s3 = 0.0f;
        #pragma unroll 8
        for (int j = 0; j < 256; j += 4) {
            s0 += r[j]; s1 += r[j + 1]; s2 += r[j + 2]; s3 += r[j + 3];
        }
        fin[t] = (s0 + s1) + (s2 + s3);
    }
    __syncthreads();

    if (t < 64) {
        float per = 0.0f;
        if (t < NBINS) {
            float c  = fin[t];
            float sc = fin[NBINS + t];
            float sa = fin[2 * NBINS + t];
            if (c > 0.0f) {
                float safe = fmaxf(c, 1.0f);
                per = (sc / safe - sa / safe) * (c * inv_n);   // (avg_conf - acc) * prop_in_bin
            }
        }
        #pragma unroll
        for (int off = 32; off > 0; off >>= 1) per += __shfl_xor(per, off);
        if (t == 0) {
            out[0] = per;
            out[1] = fin[3 * NBINS]     * inv_n;
            out[2] = fin[3 * NBINS + 1] * inv_n;
        }
    }
}

extern "C" void kernel_launch(void* const* d_in, const int* in_sizes, int n_in,
                              void* d_out, int out_size, void* d_ws, size_t ws_size,
                              hipStream_t stream) {
    const float* logits = (const float*)d_in[0];
    const int*   target = (const int*)d_in[1];
    float*       ws     = (float*)d_ws;
    float*       out    = (float*)d_out;
    const int nrows = in_sizes[1];

    // No memset: ece_rows overwrites its full partial rows, finalize reads
    // only what was written.
    ece_rows<<<GRID, BLOCK, 0, stream>>>(logits, target, ws, nrows);
    ece_finalize<<<1, 256, 0, stream>>>(ws, out, 1.0f / (float)nrows);
}